// Round 7
// baseline (66.475 us; speedup 1.0000x reference)
//
#include <hip/hip_runtime.h>
#include <math.h>

#define I_DIM 1024
#define S_DIM 512
#define O_DIM 1024
#define T_DIM 2048
#define B_SZ 4
#define M_ROWS (B_SZ * T_DIM)   // 8192
#define EPSF 1e-6f

// scan chunking: chunk length == GEMM BM (64)
#define CL 64
#define NCH 32   // NCH*CL == T_DIM

typedef _Float16 f16;
typedef __attribute__((ext_vector_type(8))) _Float16 f16x8;
typedef __attribute__((ext_vector_type(2))) _Float16 f16x2;
typedef __attribute__((ext_vector_type(4))) float f32x4;

__device__ __forceinline__ unsigned short f2h_bits(float f) {
    _Float16 h = (_Float16)f;
    return __builtin_bit_cast(unsigned short, h);
}

// async 16B global -> LDS (wave-uniform LDS base + lane*16; per-thread dest
// = base + tid*16 matches HW layout exactly -> LINEAR dest only)
__device__ __forceinline__ void load16_lds(const void* g, void* l) {
    __builtin_amdgcn_global_load_lds((const __attribute__((address_space(1))) void*)g,
                                     (__attribute__((address_space(3))) void*)l,
                                     16, 0, 0);
}

// ---------------------------------------------------------------------------
// prep: weight transposes only.
//   blocks [0,512)    : Bt16[s,i] = f16( B[i,s] * sigmoid(dt[s]) * nw[i] )
//   blocks [512,1024) : Ct16[o,s] = f16( C[s,o] )
// ---------------------------------------------------------------------------
__global__ __launch_bounds__(256)
void prep_w(const float* __restrict__ Bmat, const float* __restrict__ dt,
            const float* __restrict__ nw, unsigned short* __restrict__ Bt16,
            const float* __restrict__ Cmat, unsigned short* __restrict__ Ct16) {
    __shared__ float tile[32][33];
    const int t = threadIdx.x;
    const int tx = t & 31, ty = t >> 5;
    const int bx = blockIdx.x;
    if (bx < 512) {
        const int bs = (bx & 15) * 32;   // s block
        const int bi = (bx >> 4) * 32;   // i block
        #pragma unroll
        for (int i = ty; i < 32; i += 8)
            tile[i][tx] = Bmat[(size_t)(bi + i) * S_DIM + bs + tx];
        __syncthreads();
        const float w = nw[bi + tx];
        #pragma unroll
        for (int i = ty; i < 32; i += 8) {
            const int s = bs + i;
            const float dts = 1.0f / (1.0f + expf(-dt[s]));
            Bt16[(size_t)s * I_DIM + bi + tx] = f2h_bits(tile[tx][i] * dts * w);
        }
    } else {
        const int tb = bx - 512;
        const int bo = (tb & 31) * 32;   // o block
        const int bs = (tb >> 5) * 32;   // s block
        #pragma unroll
        for (int i = ty; i < 32; i += 8)
            tile[i][tx] = Cmat[(size_t)(bs + i) * O_DIM + bo + tx];
        __syncthreads();
        #pragma unroll
        for (int i = ty; i < 32; i += 8)
            Ct16[(size_t)(bo + i) * S_DIM + bs + tx] = f2h_bits(tile[tx][i]);
    }
}

// ---------------------------------------------------------------------------
// GEMM1 fused with RMSNorm + scan pass-1.
// up[m,s] = rs[m] * sum_i f16(u[m,i]) * f16(nw[i]*B[i,s]*dts[s])
// A-side reg-staged (cvt->f16 + sumsq); rs applied in epilogue.
// K-loop: counted vmcnt + raw barriers (B prefetch stays in flight).
// Bs both-sides XOR swizzle (rule 21): source chunk ^= f(row), read ^= f(row),
// f(r) = (r>>1)&3 -> 16-lane ds_read_b128 spreads over all 32 banks (2-way).
// chfin: chunk-final_s = sum_r a_s^(63-r) * up[m0+r, s]  (fp32, fused).
// ---------------------------------------------------------------------------
__global__ __launch_bounds__(256)
void gemm1_rms_chfin(const float* __restrict__ U, const f16* __restrict__ Bt,
                     f16* __restrict__ up, float* __restrict__ chlast,
                     const float* __restrict__ dt, const float* __restrict__ Avec) {
    constexpr int K = I_DIM, N = S_DIM, LDA = 80, NK = K / 32;
    __shared__ __align__(16) unsigned char AsB[2][64 * LDA];   // 10 KB
    __shared__ f16 Bs[2][128 * 32];                            // 16 KB
    __shared__ float rsbuf[64];
    const int t = threadIdx.x;

    // XCD swizzle: 64 consecutive tiles per XCD (16 A-panels x 4 n-blocks)
    int bid = blockIdx.x;                 // grid = 512
    bid = (bid & 7) * 64 + (bid >> 3);
    const int n0 = (bid & 3) * 128;       // 4 n-blocks
    const int m0 = (bid >> 2) * 64;       // 128 m-blocks
    const int wid = t >> 6, lane = t & 63;
    const int wn = wid * 32, lr = lane & 15, kg = lane >> 4;

    const float* aptr = U + (size_t)(m0 + (t >> 2)) * K + (t & 3) * 8;
    // B source pre-swizzle: LDS chunk (t&3) holds global chunk (t&3)^f(row)
    const int bswz = ((t & 3) ^ ((t >> 3) & 3)) * 8;
    const f16* bptr = Bt + (size_t)(n0 + (t >> 2)) * K + bswz;
    unsigned char* adst0 = &AsB[0][(t >> 2) * LDA + (t & 3) * 16];
    unsigned char* adst1 = &AsB[1][(t >> 2) * LDA + (t & 3) * 16];
    const int bread = (kg ^ ((lr >> 1) & 3)) * 8;   // read-side swizzled chunk

    float ss = 0.f;
    f32x4 acc[4][2];
    #pragma unroll
    for (int i = 0; i < 4; ++i)
        #pragma unroll
        for (int j = 0; j < 2; ++j) acc[i][j] = (f32x4){0.f, 0.f, 0.f, 0.f};

    float4 ra, rb;
    auto cvt_write = [&](unsigned char* dst) {
        ss += ra.x * ra.x + ra.y * ra.y + ra.z * ra.z + ra.w * ra.w
            + rb.x * rb.x + rb.y * rb.y + rb.z * rb.z + rb.w * rb.w;
        f16x8 h = { (_Float16)ra.x, (_Float16)ra.y, (_Float16)ra.z, (_Float16)ra.w,
                    (_Float16)rb.x, (_Float16)rb.y, (_Float16)rb.z, (_Float16)rb.w };
        *(f16x8*)dst = h;
    };

    // prologue: tile 0 staged, full drain, barrier
    load16_lds(bptr, &Bs[0][t * 8]);
    load16_lds(bptr + (size_t)64 * K, &Bs[0][2048 + t * 8]);
    ra = *(const float4*)(aptr);
    rb = *(const float4*)(aptr + 4);
    cvt_write(adst0);
    asm volatile("s_waitcnt vmcnt(0) lgkmcnt(0)");
    __builtin_amdgcn_s_barrier();

    for (int kt = 0; kt < NK; ++kt) {
        const int cur = kt & 1;
        if (kt + 1 < NK) {
            const int k1 = (kt + 1) * 32;
            ra = *(const float4*)(aptr + k1);        // A regs first (oldest)
            rb = *(const float4*)(aptr + k1 + 4);
            load16_lds(bptr + k1, &Bs[cur ^ 1][t * 8]);
            load16_lds(bptr + (size_t)64 * K + k1, &Bs[cur ^ 1][2048 + t * 8]);
            asm volatile("s_waitcnt vmcnt(4)");      // this iter's 4 stay in flight
        } else {
            asm volatile("s_waitcnt vmcnt(0)");
        }
        __builtin_amdgcn_s_barrier();                // all waves: tile kt in LDS
        __builtin_amdgcn_sched_barrier(0);

        f16x8 af[4], bf[2];
        #pragma unroll
        for (int m = 0; m < 4; ++m)
            af[m] = *(const f16x8*)&AsB[cur][(m * 16 + lr) * LDA + kg * 16];
        #pragma unroll
        for (int n = 0; n < 2; ++n)
            bf[n] = *(const f16x8*)&Bs[cur][(wn + n * 16 + lr) * 32 + bread];
        #pragma unroll
        for (int m = 0; m < 4; ++m)
            #pragma unroll
            for (int n = 0; n < 2; ++n)
                acc[m][n] = __builtin_amdgcn_mfma_f32_16x16x32_f16(af[m], bf[n], acc[m][n], 0, 0, 0);

        if (kt + 1 < NK)
            cvt_write(cur == 0 ? adst1 : adst0);     // waits vmcnt(2): ra/rb only
        asm volatile("s_waitcnt lgkmcnt(0)");        // ds_write visible
        __builtin_amdgcn_sched_barrier(0);
        __builtin_amdgcn_s_barrier();                // reads of tile kt complete
    }

    // rs per row: reduce sumsq across the 4 threads sharing a row
    ss += __shfl_xor(ss, 1, 64);
    ss += __shfl_xor(ss, 2, 64);
    if ((t & 3) == 0) rsbuf[t >> 2] = rsqrtf(ss * (1.0f / K) + EPSF);
    __syncthreads();

    // epilogue: up = rs*acc (f16) + fused chunk-final (fp32)
    const int cb = m0 >> 11;               // batch
    const int cc = (m0 >> 6) & (NCH - 1);  // chunk
    #pragma unroll
    for (int n = 0; n < 2; ++n) {
        const int col = n0 + wn + n * 16 + lr;
        const float dts = 1.0f / (1.0f + expf(-dt[col]));
        const float e = dts * fabsf(Avec[col]);
        const float ainv = expf(e);        // a^-1
        float partial = 0.f;
        #pragma unroll
        for (int m = 0; m < 4; ++m) {
            const int row = m * 16 + kg * 4;
            f32x4 rs4 = *(const f32x4*)&rsbuf[row];
            float wgt = expf(-e * (float)(63 - row));   // a^(63-row)
            #pragma unroll
            for (int j = 0; j < 4; ++j) {
                const float val = rs4[j] * acc[m][n][j];
                up[(size_t)(m0 + row + j) * N + col] = (_Float16)val;
                partial = fmaf(wgt, val, partial);
                wgt *= ainv;
            }
        }
        partial += __shfl_xor(partial, 16, 64);
        partial += __shfl_xor(partial, 32, 64);
        if (kg == 0)
            chlast[(size_t)(cb * NCH + cc) * S_DIM + col] = partial;
    }
}

// ---------------------------------------------------------------------------
// GEMM2 fused with scan pass-2:  y = x @ C + D,  x_t = a*x_{t-1} + up_t.
// Block: carry prefix -> 64-step scan -> x-tile to resident swizzled LDS ->
// K-loop (B-only staging, counted vmcnt + raw barriers, Bs XOR swizzle).
// ---------------------------------------------------------------------------
__global__ __launch_bounds__(256)
void gemm2_scan(const f16* __restrict__ upb, const float* __restrict__ chlast,
                const f16* __restrict__ Ct, const float* __restrict__ Dvec,
                const float* __restrict__ dt, const float* __restrict__ Avec,
                float* __restrict__ y, float* __restrict__ xlast) {
    constexpr int K = S_DIM, N = O_DIM, NK = K / 32;   // 16 k-steps
    __shared__ __align__(16) unsigned char As[64 * 1024];   // 64 KB x-tile
    __shared__ f16 Bs[2][128 * 32];                         // 16 KB
    const int t = threadIdx.x;

    int bid = blockIdx.x;                 // grid = 1024
    bid = (bid & 7) * 128 + (bid >> 3);
    const int n0 = (bid & 7) * 128;       // 8 n-blocks
    const int m0 = (bid >> 3) * 64;       // 128 m-blocks (= b*32 + chunk)
    const int wid = t >> 6, lane = t & 63;
    const int wn = wid * 32, lr = lane & 15, kg = lane >> 4;

    // stage B(0) early (pre-swizzled source); latency hides under carry+scan
    const int bswz = ((t & 3) ^ ((t >> 3) & 3)) * 8;
    const f16* bptr = Ct + (size_t)(n0 + (t >> 2)) * K + bswz;
    load16_lds(bptr, &Bs[0][t * 8]);
    load16_lds(bptr + (size_t)64 * K, &Bs[0][2048 + t * 8]);
    const int bread = (kg ^ ((lr >> 1) & 3)) * 8;

    // ---- carry prefix over chunk finals ----
    const int cc = (m0 >> 6) & (NCH - 1);
    const int cb = m0 >> 11;
    const int s0 = 2 * t;
    const float dts0 = 1.0f / (1.0f + expf(-dt[s0]));
    const float dts1 = 1.0f / (1.0f + expf(-dt[s0 + 1]));
    const float ab0 = fabsf(Avec[s0]), ab1 = fabsf(Avec[s0 + 1]);
    const float g0 = expf(-dts0 * ab0);
    const float g1 = expf(-dts1 * ab1);
    const float gCL0 = expf(-dts0 * ab0 * (float)CL);
    const float gCL1 = expf(-dts1 * ab1 * (float)CL);
    const float2* ch = (const float2*)chlast;
    float cy0 = 0.f, cy1 = 0.f;
    for (int j = 0; j < cc; ++j) {
        float2 f = ch[(size_t)(cb * NCH + j) * 256 + t];
        cy0 = fmaf(gCL0, cy0, f.x);
        cy1 = fmaf(gCL1, cy1, f.y);
    }

    // ---- load chunk + scan + swizzled LDS write ----
    const unsigned* up32 = (const unsigned*)upb;
    const size_t ub = (size_t)m0 * 256 + t;
    unsigned v[CL];
    #pragma unroll
    for (int j = 0; j < CL; ++j) v[j] = up32[ub + (size_t)j * 256];
    float x0 = cy0, x1 = cy1;
    #pragma unroll
    for (int j = 0; j < CL; ++j) {
        f16x2 h = __builtin_bit_cast(f16x2, v[j]);
        x0 = fmaf(g0, x0, (float)h.x);
        x1 = fmaf(g1, x1, (float)h.y);
        f16x2 o; o.x = (_Float16)x0; o.y = (_Float16)x1;
        v[j] = __builtin_bit_cast(unsigned, o);
    }
    #pragma unroll
    for (int j = 0; j < CL; ++j)
        *(unsigned*)&As[j * 1024 + ((t * 4) ^ ((j & 7) << 4))] = v[j];
    if (cc == NCH - 1)
        ((float2*)xlast)[cb * 256 + t] = make_float2(x0, x1);   // dup across n-blocks, same value
    __syncthreads();   // one-time full drain: scan ds_writes + B(0) staging

    // ---- K-loop: A resident in LDS, B double-buffered, counted vmcnt ----
    f32x4 acc[4][2];
    #pragma unroll
    for (int i = 0; i < 4; ++i)
        #pragma unroll
        for (int j = 0; j < 2; ++j) acc[i][j] = (f32x4){0.f, 0.f, 0.f, 0.f};

    const int swz = (lr & 7) << 4;        // row&7 == lr&7 for row = m*16+lr
    for (int kt = 0; kt < NK; ++kt) {
        const int cur = kt & 1;
        if (kt + 1 < NK) {
            const int k1 = (kt + 1) * 32;
            load16_lds(bptr + k1, &Bs[cur ^ 1][t * 8]);
            load16_lds(bptr + (size_t)64 * K + k1, &Bs[cur ^ 1][2048 + t * 8]);
            asm volatile("s_waitcnt vmcnt(2)");   // B[kt] done; B[kt+1] in flight
        } else {
            asm volatile("s_waitcnt vmcnt(0)");
        }
        __builtin_amdgcn_s_barrier();
        __builtin_amdgcn_sched_barrier(0);

        f16x8 af[4], bf[2];
        #pragma unroll
        for (int m = 0; m < 4; ++m)
            af[m] = *(const f16x8*)&As[(m * 16 + lr) * 1024 + ((kt * 64 + kg * 16) ^ swz)];
        #pragma unroll
        for (int n = 0; n < 2; ++n)
            bf[n] = *(const f16x8*)&Bs[cur][(wn + n * 16 + lr) * 32 + bread];
        #pragma unroll
        for (int m = 0; m < 4; ++m)
            #pragma unroll
            for (int n = 0; n < 2; ++n)
                acc[m][n] = __builtin_amdgcn_mfma_f32_16x16x32_f16(af[m], bf[n], acc[m][n], 0, 0, 0);
        __builtin_amdgcn_s_barrier();    // Bs[cur] reads done before restage
    }

    // epilogue: y = acc + D
    #pragma unroll
    for (int n = 0; n < 2; ++n) {
        const int col = n0 + wn + n * 16 + lr;
        const float dv = Dvec[col];
        #pragma unroll
        for (int m = 0; m < 4; ++m) {
            const int row = m0 + m * 16 + kg * 4;
            #pragma unroll
            for (int j = 0; j < 4; ++j)
                y[(size_t)(row + j) * N + col] = acc[m][n][j] + dv;
        }
    }
}

// ---------------------------------------------------------------------------
extern "C" void kernel_launch(void* const* d_in, const int* in_sizes, int n_in,
                              void* d_out, int out_size, void* d_ws, size_t ws_size,
                              hipStream_t stream) {
    const float* u    = (const float*)d_in[0];   // [B,T,I]
    const float* dt   = (const float*)d_in[1];   // [S]
    const float* Avec = (const float*)d_in[2];   // [S]
    const float* Bmat = (const float*)d_in[3];   // [I,S]
    const float* Cmat = (const float*)d_in[4];   // [S,O]
    const float* Dvec = (const float*)d_in[5];   // [O]
    const float* nw   = (const float*)d_in[6];   // [I]

    float* y     = (float*)d_out;                      // [B,T,O] fp32
    float* xlast = y + (size_t)M_ROWS * O_DIM;         // [B,S]   fp32

    // workspace (~10.7 MB)
    char* w = (char*)d_ws;
    f16*            up16   = (f16*)(w);                          // [8192,512] f16
    unsigned short* Bt16   = (unsigned short*)(w + 8388608);     // [512,1024] f16 (dts,nw folded)
    unsigned short* Ct16   = (unsigned short*)(w + 9437184);     // [1024,512] f16
    float*          chlast = (float*)(w + 10485760);             // [B,NCH,S] fp32

    // 1. weight transposes
    prep_w<<<1024, 256, 0, stream>>>(Bmat, dt, nw, Bt16, Cmat, Ct16);

    // 2. GEMM1 (+rmsnorm +chunk-finals): up16, chlast
    gemm1_rms_chfin<<<512, 256, 0, stream>>>(u, (const f16*)Bt16, up16, chlast, dt, Avec);

    // 3. GEMM2 (+carry +scan): y, xlast
    gemm2_scan<<<1024, 256, 0, stream>>>(up16, chlast, (const f16*)Ct16, Dvec,
                                         dt, Avec, y, xlast);
}

// Round 8
// 59.774 us; speedup vs baseline: 1.1121x; 1.1121x over previous
//
#include <hip/hip_runtime.h>
#include <math.h>

#define I_DIM 1024
#define S_DIM 512
#define O_DIM 1024
#define T_DIM 2048
#define B_SZ 4
#define M_ROWS (B_SZ * T_DIM)   // 8192
#define EPSF 1e-6f

// scan chunking: chunk length == GEMM BM (64)
#define CL 64
#define NCH 32   // NCH*CL == T_DIM

typedef _Float16 f16;
typedef __attribute__((ext_vector_type(8))) _Float16 f16x8;
typedef __attribute__((ext_vector_type(2))) _Float16 f16x2;
typedef __attribute__((ext_vector_type(4))) float f32x4;

__device__ __forceinline__ unsigned short f2h_bits(float f) {
    _Float16 h = (_Float16)f;
    return __builtin_bit_cast(unsigned short, h);
}

// async 16B global -> LDS (wave-uniform LDS base + lane*16; per-thread dest
// = base + tid*16 matches HW layout exactly -> LINEAR dest only)
__device__ __forceinline__ void load16_lds(const void* g, void* l) {
    __builtin_amdgcn_global_load_lds((const __attribute__((address_space(1))) void*)g,
                                     (__attribute__((address_space(3))) void*)l,
                                     16, 0, 0);
}

// ---------------------------------------------------------------------------
// prep: RMSNorm->u16 (rs folded)  +  B^T (dts,nw folded)  +  C^T.
//   blocks [0, 8192)        : rmsnorm rows -> u16[m,i] = f16(u[m,i] * rs[m])
//   blocks [8192, 8704)     : Bt16[s,i] = f16( B[i,s] * sigmoid(dt[s]) * nw[i] )
//   blocks [8704, 9216)     : Ct16[o,s] = f16( C[s,o] )
// All streaming, latency-tolerant — keeps the fp32->f16 chain OUT of the GEMMs.
// ---------------------------------------------------------------------------
__global__ __launch_bounds__(256)
void prep(const float* __restrict__ u, const float* __restrict__ nw,
          unsigned short* __restrict__ u16,
          const float* __restrict__ Bmat, const float* __restrict__ dt,
          unsigned short* __restrict__ Bt16,
          const float* __restrict__ Cmat, unsigned short* __restrict__ Ct16) {
    __shared__ float tile[32][33];
    const int t = threadIdx.x;
    const int bx = blockIdx.x;

    if (bx < M_ROWS) {
        float4 v = ((const float4*)(u + (size_t)bx * I_DIM))[t];
        float ss = v.x * v.x + v.y * v.y + v.z * v.z + v.w * v.w;
        #pragma unroll
        for (int off = 32; off > 0; off >>= 1) ss += __shfl_down(ss, off, 64);
        if ((t & 63) == 0) tile[0][t >> 6] = ss;
        __syncthreads();
        if (t == 0)
            tile[0][0] = rsqrtf((tile[0][0] + tile[0][1] + tile[0][2] + tile[0][3])
                                * (1.0f / I_DIM) + EPSF);
        __syncthreads();
        const float rs = tile[0][0];
        ushort4 o;
        o.x = f2h_bits(v.x * rs);
        o.y = f2h_bits(v.y * rs);
        o.z = f2h_bits(v.z * rs);
        o.w = f2h_bits(v.w * rs);
        ((ushort4*)(u16 + (size_t)bx * I_DIM))[t] = o;
    } else if (bx < M_ROWS + 512) {
        const int tb = bx - M_ROWS;
        const int bs = (tb & 15) * 32;   // s block
        const int bi = (tb >> 4) * 32;   // i block
        const int tx = t & 31, ty = t >> 5;
        #pragma unroll
        for (int i = ty; i < 32; i += 8)
            tile[i][tx] = Bmat[(size_t)(bi + i) * S_DIM + bs + tx];
        __syncthreads();
        const float w = nw[bi + tx];
        #pragma unroll
        for (int i = ty; i < 32; i += 8) {
            const int s = bs + i;
            const float dts = 1.0f / (1.0f + expf(-dt[s]));
            Bt16[(size_t)s * I_DIM + bi + tx] = f2h_bits(tile[tx][i] * dts * w);
        }
    } else {
        const int tb = bx - M_ROWS - 512;
        const int bo = (tb & 31) * 32;   // o block
        const int bs = (tb >> 5) * 32;   // s block
        const int tx = t & 31, ty = t >> 5;
        #pragma unroll
        for (int i = ty; i < 32; i += 8)
            tile[i][tx] = Cmat[(size_t)(bs + i) * O_DIM + bo + tx];
        __syncthreads();
        #pragma unroll
        for (int i = ty; i < 32; i += 8)
            Ct16[(size_t)(bo + i) * S_DIM + bs + tx] = f2h_bits(tile[tx][i]);
    }
}

// ---------------------------------------------------------------------------
// GEMM1 + fused scan pass-1 (chunk finals).  up = u16 @ Bt16^T.
// 64x128 tile, 4 waves (64x32 each), 3-deep single-barrier pipeline:
//   vmcnt(3) [tile kt landed, kt+1 in flight] -> s_barrier -> stage(kt+2)
//   -> ds_read -> 8 MFMA.  No lgkmcnt, no drain, 1 barrier/iter.
// Both A and B staged via global_load_lds with source-side XOR pre-swizzle
// (rule 21): LDS chunk c holds global chunk c ^ ((row>>1)&3); read chunk
// kg ^ ((lr>>1)&3)  -> 16-lane ds_read_b128 spreads to 2-way (free).
// ---------------------------------------------------------------------------
__global__ __launch_bounds__(256)
void gemm1_chfin(const f16* __restrict__ A, const f16* __restrict__ Bt,
                 f16* __restrict__ up, float* __restrict__ chlast,
                 const float* __restrict__ dt, const float* __restrict__ Avec) {
    constexpr int K = I_DIM, N = S_DIM, NK = K / 32;   // 32 k-steps
    __shared__ f16 As[3][64 * 32];    // 3 x 4 KB
    __shared__ f16 Bs[3][128 * 32];   // 3 x 8 KB
    const int t = threadIdx.x;

    // XCD swizzle (512 = 8*64): consecutive tiles on one XCD share A panels
    int bid = blockIdx.x;
    bid = (bid & 7) * 64 + (bid >> 3);
    const int n0 = (bid & 3) * 128;       // 4 n-blocks
    const int m0 = (bid >> 2) * 64;       // 128 m-blocks
    const int wid = t >> 6, lane = t & 63;
    const int wn = wid * 32, lr = lane & 15, kg = lane >> 4;

    const int srcswz = ((t & 3) ^ ((t >> 3) & 3)) * 8;   // f16 units
    const f16* aptr = A + (size_t)(m0 + (t >> 2)) * K + srcswz;
    const f16* bptr = Bt + (size_t)(n0 + (t >> 2)) * K + srcswz;
    const int rchunk = (kg ^ ((lr >> 1) & 3)) * 8;       // read-side chunk

    f32x4 acc[4][2];
    #pragma unroll
    for (int i = 0; i < 4; ++i)
        #pragma unroll
        for (int j = 0; j < 2; ++j) acc[i][j] = (f32x4){0.f, 0.f, 0.f, 0.f};

    auto stage = [&](int kt, int buf) {
        const int k0 = kt * 32;
        load16_lds(aptr + k0, &As[buf][t * 8]);
        load16_lds(bptr + k0, &Bs[buf][t * 8]);
        load16_lds(bptr + (size_t)64 * K + k0, &Bs[buf][2048 + t * 8]);
    };

    stage(0, 0);
    stage(1, 1);
    int bcur = 0, bst = 2;
    for (int kt = 0; kt < NK; ++kt) {
        if (kt + 1 < NK) asm volatile("s_waitcnt vmcnt(3)");  // tile kt landed
        else             asm volatile("s_waitcnt vmcnt(0)");
        __builtin_amdgcn_s_barrier();          // all waves' tile kt in LDS;
        __builtin_amdgcn_sched_barrier(0);     // prev iter's reads retired
        if (kt + 2 < NK) stage(kt + 2, bst);   // into buf read 3 iters away

        f16x8 af[4], bf[2];
        #pragma unroll
        for (int m = 0; m < 4; ++m)
            af[m] = *(const f16x8*)&As[bcur][(m * 16 + lr) * 32 + rchunk];
        #pragma unroll
        for (int n = 0; n < 2; ++n)
            bf[n] = *(const f16x8*)&Bs[bcur][(wn + n * 16 + lr) * 32 + rchunk];
        #pragma unroll
        for (int m = 0; m < 4; ++m)
            #pragma unroll
            for (int n = 0; n < 2; ++n)
                acc[m][n] = __builtin_amdgcn_mfma_f32_16x16x32_f16(af[m], bf[n], acc[m][n], 0, 0, 0);

        bcur = (bcur == 2) ? 0 : bcur + 1;
        bst  = (bst  == 2) ? 0 : bst  + 1;
    }

    // epilogue: up (f16) + fused chunk-final (fp32)
    // C/D layout: col = lane&15, row = (lane>>4)*4 + reg
    const int cb = m0 >> 11;               // batch
    const int cc = (m0 >> 6) & (NCH - 1);  // chunk
    #pragma unroll
    for (int n = 0; n < 2; ++n) {
        const int col = n0 + wn + n * 16 + lr;
        const float dts = 1.0f / (1.0f + expf(-dt[col]));
        const float e = dts * fabsf(Avec[col]);
        const float ainv = expf(e);        // a^-1
        float partial = 0.f;
        #pragma unroll
        for (int m = 0; m < 4; ++m) {
            const int row = m * 16 + kg * 4;
            float wgt = expf(-e * (float)(63 - row));   // a^(63-row)
            #pragma unroll
            for (int j = 0; j < 4; ++j) {
                const float val = acc[m][n][j];
                up[(size_t)(m0 + row + j) * N + col] = (_Float16)val;
                partial = fmaf(wgt, val, partial);
                wgt *= ainv;
            }
        }
        partial += __shfl_xor(partial, 16, 64);
        partial += __shfl_xor(partial, 32, 64);
        if (kg == 0)
            chlast[(size_t)(cb * NCH + cc) * S_DIM + col] = partial;
    }
}

// ---------------------------------------------------------------------------
// GEMM2 fused with scan pass-2:  y = x @ C + D,  x_t = a*x_{t-1} + up_t.
// Block: batched carry prefix -> 64-step scan -> x-tile to resident swizzled
// LDS -> K-loop (B 2-buf staging, counted vmcnt, raw barriers).
// ---------------------------------------------------------------------------
__global__ __launch_bounds__(256)
void gemm2_scan(const f16* __restrict__ upb, const float* __restrict__ chlast,
                const f16* __restrict__ Ct, const float* __restrict__ Dvec,
                const float* __restrict__ dt, const float* __restrict__ Avec,
                float* __restrict__ y, float* __restrict__ xlast) {
    constexpr int K = S_DIM, N = O_DIM, NK = K / 32;   // 16 k-steps
    __shared__ __align__(16) unsigned char As[64 * 1024];   // 64 KB x-tile
    __shared__ f16 Bs[2][128 * 32];                         // 16 KB
    const int t = threadIdx.x;

    int bid = blockIdx.x;                 // grid = 1024
    bid = (bid & 7) * 128 + (bid >> 3);
    const int n0 = (bid & 7) * 128;       // 8 n-blocks
    const int m0 = (bid >> 3) * 64;       // 128 m-blocks (= b*32 + chunk)
    const int wid = t >> 6, lane = t & 63;
    const int wn = wid * 32, lr = lane & 15, kg = lane >> 4;

    // stage B(0) early (pre-swizzled source); latency hides under carry+scan
    const int srcswz = ((t & 3) ^ ((t >> 3) & 3)) * 8;
    const f16* bptr = Ct + (size_t)(n0 + (t >> 2)) * K + srcswz;
    load16_lds(bptr, &Bs[0][t * 8]);
    load16_lds(bptr + (size_t)64 * K, &Bs[0][2048 + t * 8]);
    const int rchunk = (kg ^ ((lr >> 1) & 3)) * 8;

    // ---- carry prefix over chunk finals (batched independent loads) ----
    const int cc = (m0 >> 6) & (NCH - 1);
    const int cb = m0 >> 11;
    const int s0 = 2 * t;
    const float dts0 = 1.0f / (1.0f + expf(-dt[s0]));
    const float dts1 = 1.0f / (1.0f + expf(-dt[s0 + 1]));
    const float ab0 = fabsf(Avec[s0]), ab1 = fabsf(Avec[s0 + 1]);
    const float g0 = expf(-dts0 * ab0);
    const float g1 = expf(-dts1 * ab1);
    const float gCL0 = expf(-dts0 * ab0 * (float)CL);
    const float gCL1 = expf(-dts1 * ab1 * (float)CL);
    const float2* ch = (const float2*)chlast;
    float cy0 = 0.f, cy1 = 0.f;
    {
        int j = 0;
        for (; j + 4 <= cc; j += 4) {
            float2 f0 = ch[(size_t)(cb * NCH + j + 0) * 256 + t];
            float2 f1 = ch[(size_t)(cb * NCH + j + 1) * 256 + t];
            float2 f2 = ch[(size_t)(cb * NCH + j + 2) * 256 + t];
            float2 f3 = ch[(size_t)(cb * NCH + j + 3) * 256 + t];
            cy0 = fmaf(gCL0, cy0, f0.x); cy1 = fmaf(gCL1, cy1, f0.y);
            cy0 = fmaf(gCL0, cy0, f1.x); cy1 = fmaf(gCL1, cy1, f1.y);
            cy0 = fmaf(gCL0, cy0, f2.x); cy1 = fmaf(gCL1, cy1, f2.y);
            cy0 = fmaf(gCL0, cy0, f3.x); cy1 = fmaf(gCL1, cy1, f3.y);
        }
        for (; j < cc; ++j) {
            float2 f = ch[(size_t)(cb * NCH + j) * 256 + t];
            cy0 = fmaf(gCL0, cy0, f.x);
            cy1 = fmaf(gCL1, cy1, f.y);
        }
    }

    // ---- load chunk + scan + swizzled LDS write ----
    const unsigned* up32 = (const unsigned*)upb;
    const size_t ub = (size_t)m0 * 256 + t;
    unsigned v[CL];
    #pragma unroll
    for (int j = 0; j < CL; ++j) v[j] = up32[ub + (size_t)j * 256];
    float x0 = cy0, x1 = cy1;
    #pragma unroll
    for (int j = 0; j < CL; ++j) {
        f16x2 h = __builtin_bit_cast(f16x2, v[j]);
        x0 = fmaf(g0, x0, (float)h.x);
        x1 = fmaf(g1, x1, (float)h.y);
        f16x2 o; o.x = (_Float16)x0; o.y = (_Float16)x1;
        v[j] = __builtin_bit_cast(unsigned, o);
    }
    #pragma unroll
    for (int j = 0; j < CL; ++j)
        *(unsigned*)&As[j * 1024 + ((t * 4) ^ ((j & 7) << 4))] = v[j];
    if (cc == NCH - 1)
        ((float2*)xlast)[cb * 256 + t] = make_float2(x0, x1);   // dup across n-blocks, same value
    __syncthreads();   // one-time full drain: scan ds_writes + B(0) staging

    // ---- K-loop: A resident in LDS, B double-buffered, counted vmcnt ----
    f32x4 acc[4][2];
    #pragma unroll
    for (int i = 0; i < 4; ++i)
        #pragma unroll
        for (int j = 0; j < 2; ++j) acc[i][j] = (f32x4){0.f, 0.f, 0.f, 0.f};

    const int swz = (lr & 7) << 4;        // row&7 == lr&7 for row = m*16+lr
    for (int kt = 0; kt < NK; ++kt) {
        const int cur = kt & 1;
        if (kt + 1 < NK) {
            const int k1 = (kt + 1) * 32;
            load16_lds(bptr + k1, &Bs[cur ^ 1][t * 8]);
            load16_lds(bptr + (size_t)64 * K + k1, &Bs[cur ^ 1][2048 + t * 8]);
            asm volatile("s_waitcnt vmcnt(2)");   // B[kt] done; B[kt+1] in flight
        } else {
            asm volatile("s_waitcnt vmcnt(0)");
        }
        __builtin_amdgcn_s_barrier();
        __builtin_amdgcn_sched_barrier(0);

        f16x8 af[4], bf[2];
        #pragma unroll
        for (int m = 0; m < 4; ++m)
            af[m] = *(const f16x8*)&As[(m * 16 + lr) * 1024 + ((kt * 64 + kg * 16) ^ swz)];
        #pragma unroll
        for (int n = 0; n < 2; ++n)
            bf[n] = *(const f16x8*)&Bs[cur][(wn + n * 16 + lr) * 32 + rchunk];
        #pragma unroll
        for (int m = 0; m < 4; ++m)
            #pragma unroll
            for (int n = 0; n < 2; ++n)
                acc[m][n] = __builtin_amdgcn_mfma_f32_16x16x32_f16(af[m], bf[n], acc[m][n], 0, 0, 0);
        __builtin_amdgcn_s_barrier();    // Bs[cur] reads done before restage
    }

    // epilogue: y = acc + D
    #pragma unroll
    for (int n = 0; n < 2; ++n) {
        const int col = n0 + wn + n * 16 + lr;
        const float dv = Dvec[col];
        #pragma unroll
        for (int m = 0; m < 4; ++m) {
            const int row = m0 + m * 16 + kg * 4;
            #pragma unroll
            for (int j = 0; j < 4; ++j)
                y[(size_t)(row + j) * N + col] = acc[m][n][j] + dv;
        }
    }
}

// ---------------------------------------------------------------------------
extern "C" void kernel_launch(void* const* d_in, const int* in_sizes, int n_in,
                              void* d_out, int out_size, void* d_ws, size_t ws_size,
                              hipStream_t stream) {
    const float* u    = (const float*)d_in[0];   // [B,T,I]
    const float* dt   = (const float*)d_in[1];   // [S]
    const float* Avec = (const float*)d_in[2];   // [S]
    const float* Bmat = (const float*)d_in[3];   // [I,S]
    const float* Cmat = (const float*)d_in[4];   // [S,O]
    const float* Dvec = (const float*)d_in[5];   // [O]
    const float* nw   = (const float*)d_in[6];   // [I]

    float* y     = (float*)d_out;                      // [B,T,O] fp32
    float* xlast = y + (size_t)M_ROWS * O_DIM;         // [B,S]   fp32

    // workspace (~27.5 MB)
    char* w = (char*)d_ws;
    unsigned short* u16    = (unsigned short*)(w);               // [8192,1024] f16 (rs folded)
    f16*            up16   = (f16*)(w + 16777216);               // [8192,512]  f16
    unsigned short* Bt16   = (unsigned short*)(w + 25165824);    // [512,1024]  f16 (dts,nw folded)
    unsigned short* Ct16   = (unsigned short*)(w + 26214400);    // [1024,512]  f16
    float*          chlast = (float*)(w + 27262976);             // [B,NCH,S]   fp32

    // 1. prep: rmsnorm->u16 + weight transposes
    prep<<<M_ROWS + 512 + 512, 256, 0, stream>>>(u, nw, u16, Bmat, dt, Bt16, Cmat, Ct16);

    // 2. GEMM1 (+chunk finals): up16 = u16 @ Bt, chlast
    gemm1_chfin<<<512, 256, 0, stream>>>((const f16*)u16, (const f16*)Bt16,
                                         up16, chlast, dt, Avec);

    // 3. GEMM2 (+carry +scan): y, xlast
    gemm2_scan<<<1024, 256, 0, stream>>>(up16, chlast, (const f16*)Ct16, Dvec,
                                         dt, Avec, y, xlast);
}

// Round 9
// 56.493 us; speedup vs baseline: 1.1767x; 1.0581x over previous
//
#include <hip/hip_runtime.h>
#include <math.h>

#define I_DIM 1024
#define S_DIM 512
#define O_DIM 1024
#define T_DIM 2048
#define B_SZ 4
#define M_ROWS (B_SZ * T_DIM)   // 8192
#define EPSF 1e-6f

// scan chunking: chunk length == GEMM BM (64)
#define CL 64
#define NCH 32   // NCH*CL == T_DIM

typedef _Float16 f16;
typedef __attribute__((ext_vector_type(8))) _Float16 f16x8;
typedef __attribute__((ext_vector_type(2))) _Float16 f16x2;
typedef __attribute__((ext_vector_type(4))) float f32x4;

__device__ __forceinline__ unsigned short f2h_bits(float f) {
    _Float16 h = (_Float16)f;
    return __builtin_bit_cast(unsigned short, h);
}

// async 16B global -> LDS (wave-uniform LDS base + lane*16; per-thread dest
// = base + tid*16 matches HW layout exactly -> LINEAR dest only)
__device__ __forceinline__ void load16_lds(const void* g, void* l) {
    __builtin_amdgcn_global_load_lds((const __attribute__((address_space(1))) void*)g,
                                     (__attribute__((address_space(3))) void*)l,
                                     16, 0, 0);
}

// ---------------------------------------------------------------------------
// prep: weight transposes only (u handled inside gemm1 now).
//   blocks [0,512)    : Bt16[s,i] = f16( B[i,s] * sigmoid(dt[s]) * nw[i] )
//   blocks [512,1024) : Ct16[o,s] = f16( C[s,o] )
// ---------------------------------------------------------------------------
__global__ __launch_bounds__(256)
void prep_w(const float* __restrict__ Bmat, const float* __restrict__ dt,
            const float* __restrict__ nw, unsigned short* __restrict__ Bt16,
            const float* __restrict__ Cmat, unsigned short* __restrict__ Ct16) {
    __shared__ float tile[32][33];
    const int t = threadIdx.x;
    const int tx = t & 31, ty = t >> 5;
    const int bx = blockIdx.x;
    if (bx < 512) {
        const int bs = (bx & 15) * 32;   // s block
        const int bi = (bx >> 4) * 32;   // i block
        #pragma unroll
        for (int i = ty; i < 32; i += 8)
            tile[i][tx] = Bmat[(size_t)(bi + i) * S_DIM + bs + tx];
        __syncthreads();
        const float w = nw[bi + tx];
        #pragma unroll
        for (int i = ty; i < 32; i += 8) {
            const int s = bs + i;
            const float dts = 1.0f / (1.0f + expf(-dt[s]));
            Bt16[(size_t)s * I_DIM + bi + tx] = f2h_bits(tile[tx][i] * dts * w);
        }
    } else {
        const int tb = bx - 512;
        const int bo = (tb & 31) * 32;   // o block
        const int bs = (tb >> 5) * 32;   // s block
        #pragma unroll
        for (int i = ty; i < 32; i += 8)
            tile[i][tx] = Cmat[(size_t)(bs + i) * O_DIM + bo + tx];
        __syncthreads();
        #pragma unroll
        for (int i = ty; i < 32; i += 8)
            Ct16[(size_t)(bo + i) * S_DIM + bs + tx] = f2h_bits(tile[tx][i]);
    }
}

// ---------------------------------------------------------------------------
// GEMM1 fused with RMSNorm + scan pass-1.  Reads fp32 u DIRECTLY.
// up[m,s] = rs[m] * sum_i f16(u[m,i]) * Bt[s,i],  rs from in-loop sumsq.
// Pipeline (3 LDS bufs, 1 barrier/iter, T14 issue-early/write-late):
//   iter kt: vmcnt(2) [retires B(kt) lds + A(kt+1) regs; B(kt+1),B(kt+2) fly]
//   -> barrier -> ds_write A(kt+1) (cvt f32->f16 + sumsq) -> issue A(kt+2)
//   reg-loads + B(kt+2) gl_lds -> ds_read frags tile kt -> 8 MFMA.
// Load order per iter: A-regs FIRST then B-gl_lds (vmcnt retire order).
// Both-sides XOR chunk swizzle on As/Bs (rule 21).
// ---------------------------------------------------------------------------
__global__ __launch_bounds__(256)
void gemm1_rms_chfin(const float* __restrict__ U, const f16* __restrict__ Bt,
                     f16* __restrict__ up, float* __restrict__ chlast,
                     const float* __restrict__ dt, const float* __restrict__ Avec) {
    constexpr int K = I_DIM, N = S_DIM, NK = K / 32;   // 32 k-steps
    __shared__ f16 As[3][64 * 32];    // 12 KB
    __shared__ f16 Bs[3][128 * 32];   // 24 KB
    __shared__ float rsbuf[64];
    const int t = threadIdx.x;

    // XCD swizzle (512 = 8*64): 4 consecutive bids share an A panel -> same XCD
    int bid = blockIdx.x;
    bid = (bid & 7) * 64 + (bid >> 3);
    const int n0 = (bid & 3) * 128;       // 4 n-blocks
    const int m0 = (bid >> 2) * 64;       // 128 m-blocks
    const int wid = t >> 6, lane = t & 63;
    const int wn = wid * 32, lr = lane & 15, kg = lane >> 4;

    // source-side chunk swizzle (matches read side): chunk c holds global c^f(row)
    const int swch = (t & 3) ^ ((t >> 3) & 3);
    const float* aptr = U + (size_t)(m0 + (t >> 2)) * K + swch * 8;   // fp32 rows
    const f16*  bptr = Bt + (size_t)(n0 + (t >> 2)) * K + swch * 8;   // f16 rows
    const int rchunk = (kg ^ ((lr >> 1) & 3)) * 8;       // read-side chunk
    f16* adst = (f16*)&As[0][0] + t * 8;                 // + slot*2048

    float ss = 0.f;
    f32x4 acc[4][2];
    #pragma unroll
    for (int i = 0; i < 4; ++i)
        #pragma unroll
        for (int j = 0; j < 2; ++j) acc[i][j] = (f32x4){0.f, 0.f, 0.f, 0.f};

    float4 rga[2], rgb[2];   // two A reg sets (8 floats each)

    auto stageB = [&](int kt, int slot) {
        load16_lds(bptr + kt * 32, &Bs[slot][t * 8]);
        load16_lds(bptr + (size_t)64 * K + kt * 32, &Bs[slot][2048 + t * 8]);
    };
    auto writeA = [&](const float4* r, int slot) {
        ss += r[0].x * r[0].x + r[0].y * r[0].y + r[0].z * r[0].z + r[0].w * r[0].w
            + r[1].x * r[1].x + r[1].y * r[1].y + r[1].z * r[1].z + r[1].w * r[1].w;
        f16x8 h = { (_Float16)r[0].x, (_Float16)r[0].y, (_Float16)r[0].z, (_Float16)r[0].w,
                    (_Float16)r[1].x, (_Float16)r[1].y, (_Float16)r[1].z, (_Float16)r[1].w };
        *(f16x8*)(adst + slot * 2048) = h;
    };

    // prologue: A(0)->rga, B(0); A(1)->rgb, B(1); write A(0)
    rga[0] = *(const float4*)(aptr);
    rga[1] = *(const float4*)(aptr + 4);
    stageB(0, 0);
    rgb[0] = *(const float4*)(aptr + 32);
    rgb[1] = *(const float4*)(aptr + 36);
    stageB(1, 1);
    asm volatile("s_waitcnt vmcnt(6)");    // rga (A0) landed
    writeA(rga, 0);

    #pragma unroll 2
    for (int kt = 0; kt < NK; ++kt) {
        asm volatile("s_waitcnt lgkmcnt(0)");          // my ds_write drained
        if (kt + 1 < NK) asm volatile("s_waitcnt vmcnt(2)");
        else             asm volatile("s_waitcnt vmcnt(0)");
        __builtin_amdgcn_s_barrier();                  // tile kt fully in LDS
        __builtin_amdgcn_sched_barrier(0);

        if (kt + 1 < NK)
            writeA(((kt + 1) & 1) ? rgb : rga, (kt + 1) % 3);
        if (kt + 2 < NK) {
            float4* r = (kt & 1) ? rgb : rga;          // set freed by writeA(kt+1-1)
            const int k2 = (kt + 2) * 32;
            r[0] = *(const float4*)(aptr + k2);        // A regs first (retire first)
            r[1] = *(const float4*)(aptr + k2 + 4);
            stageB(kt + 2, (kt + 2) % 3);
        }

        const int slot = kt % 3;
        f16x8 af[4], bf[2];
        #pragma unroll
        for (int m = 0; m < 4; ++m)
            af[m] = *(const f16x8*)&As[slot][(m * 16 + lr) * 32 + rchunk];
        #pragma unroll
        for (int n = 0; n < 2; ++n)
            bf[n] = *(const f16x8*)&Bs[slot][(wn + n * 16 + lr) * 32 + rchunk];
        #pragma unroll
        for (int m = 0; m < 4; ++m)
            #pragma unroll
            for (int n = 0; n < 2; ++n)
                acc[m][n] = __builtin_amdgcn_mfma_f32_16x16x32_f16(af[m], bf[n], acc[m][n], 0, 0, 0);
    }

    // rs per row: thread's ss covers its 256 staged elements of row t>>2;
    // 4 threads per row -> xor-reduce
    ss += __shfl_xor(ss, 1, 64);
    ss += __shfl_xor(ss, 2, 64);
    if ((t & 3) == 0) rsbuf[t >> 2] = rsqrtf(ss * (1.0f / K) + EPSF);
    __syncthreads();

    // epilogue: up = rs*acc (f16) + fused chunk-final (fp32)
    // C/D layout: col = lane&15, row = (lane>>4)*4 + reg
    const int cb = m0 >> 11;               // batch
    const int cc = (m0 >> 6) & (NCH - 1);  // chunk
    #pragma unroll
    for (int n = 0; n < 2; ++n) {
        const int col = n0 + wn + n * 16 + lr;
        const float dts = 1.0f / (1.0f + expf(-dt[col]));
        const float e = dts * fabsf(Avec[col]);
        const float ainv = expf(e);        // a^-1
        float partial = 0.f;
        #pragma unroll
        for (int m = 0; m < 4; ++m) {
            const int row = m * 16 + kg * 4;
            f32x4 rs4 = *(const f32x4*)&rsbuf[row];
            float wgt = expf(-e * (float)(63 - row));   // a^(63-row)
            #pragma unroll
            for (int j = 0; j < 4; ++j) {
                const float val = rs4[j] * acc[m][n][j];
                up[(size_t)(m0 + row + j) * N + col] = (_Float16)val;
                partial = fmaf(wgt, val, partial);
                wgt *= ainv;
            }
        }
        partial += __shfl_xor(partial, 16, 64);
        partial += __shfl_xor(partial, 32, 64);
        if (kg == 0)
            chlast[(size_t)(cb * NCH + cc) * S_DIM + col] = partial;
    }
}

// ---------------------------------------------------------------------------
// GEMM2 fused with scan pass-2:  y = x @ C + D,  x_t = a*x_{t-1} + up_t.
// Block: batched carry prefix -> 64-step scan -> x-tile to resident swizzled
// LDS -> K-loop (B 2-buf staging, counted vmcnt, raw barriers).
// ---------------------------------------------------------------------------
__global__ __launch_bounds__(256)
void gemm2_scan(const f16* __restrict__ upb, const float* __restrict__ chlast,
                const f16* __restrict__ Ct, const float* __restrict__ Dvec,
                const float* __restrict__ dt, const float* __restrict__ Avec,
                float* __restrict__ y, float* __restrict__ xlast) {
    constexpr int K = S_DIM, N = O_DIM, NK = K / 32;   // 16 k-steps
    __shared__ __align__(16) unsigned char As[64 * 1024];   // 64 KB x-tile
    __shared__ f16 Bs[2][128 * 32];                         // 16 KB
    const int t = threadIdx.x;

    int bid = blockIdx.x;                 // grid = 1024
    bid = (bid & 7) * 128 + (bid >> 3);
    const int n0 = (bid & 7) * 128;       // 8 n-blocks
    const int m0 = (bid >> 3) * 64;       // 128 m-blocks (= b*32 + chunk)
    const int wid = t >> 6, lane = t & 63;
    const int wn = wid * 32, lr = lane & 15, kg = lane >> 4;

    // stage B(0) early (pre-swizzled source); latency hides under carry+scan
    const int srcswz = ((t & 3) ^ ((t >> 3) & 3)) * 8;
    const f16* bptr = Ct + (size_t)(n0 + (t >> 2)) * K + srcswz;
    load16_lds(bptr, &Bs[0][t * 8]);
    load16_lds(bptr + (size_t)64 * K, &Bs[0][2048 + t * 8]);
    const int rchunk = (kg ^ ((lr >> 1) & 3)) * 8;

    // ---- carry prefix over chunk finals (batched independent loads) ----
    const int cc = (m0 >> 6) & (NCH - 1);
    const int cb = m0 >> 11;
    const int s0 = 2 * t;
    const float dts0 = 1.0f / (1.0f + expf(-dt[s0]));
    const float dts1 = 1.0f / (1.0f + expf(-dt[s0 + 1]));
    const float ab0 = fabsf(Avec[s0]), ab1 = fabsf(Avec[s0 + 1]);
    const float g0 = expf(-dts0 * ab0);
    const float g1 = expf(-dts1 * ab1);
    const float gCL0 = expf(-dts0 * ab0 * (float)CL);
    const float gCL1 = expf(-dts1 * ab1 * (float)CL);
    const float2* ch = (const float2*)chlast;
    float cy0 = 0.f, cy1 = 0.f;
    {
        int j = 0;
        for (; j + 4 <= cc; j += 4) {
            float2 f0 = ch[(size_t)(cb * NCH + j + 0) * 256 + t];
            float2 f1 = ch[(size_t)(cb * NCH + j + 1) * 256 + t];
            float2 f2 = ch[(size_t)(cb * NCH + j + 2) * 256 + t];
            float2 f3 = ch[(size_t)(cb * NCH + j + 3) * 256 + t];
            cy0 = fmaf(gCL0, cy0, f0.x); cy1 = fmaf(gCL1, cy1, f0.y);
            cy0 = fmaf(gCL0, cy0, f1.x); cy1 = fmaf(gCL1, cy1, f1.y);
            cy0 = fmaf(gCL0, cy0, f2.x); cy1 = fmaf(gCL1, cy1, f2.y);
            cy0 = fmaf(gCL0, cy0, f3.x); cy1 = fmaf(gCL1, cy1, f3.y);
        }
        for (; j < cc; ++j) {
            float2 f = ch[(size_t)(cb * NCH + j) * 256 + t];
            cy0 = fmaf(gCL0, cy0, f.x);
            cy1 = fmaf(gCL1, cy1, f.y);
        }
    }

    // ---- load chunk + scan + swizzled LDS write ----
    const unsigned* up32 = (const unsigned*)upb;
    const size_t ub = (size_t)m0 * 256 + t;
    unsigned v[CL];
    #pragma unroll
    for (int j = 0; j < CL; ++j) v[j] = up32[ub + (size_t)j * 256];
    float x0 = cy0, x1 = cy1;
    #pragma unroll
    for (int j = 0; j < CL; ++j) {
        f16x2 h = __builtin_bit_cast(f16x2, v[j]);
        x0 = fmaf(g0, x0, (float)h.x);
        x1 = fmaf(g1, x1, (float)h.y);
        f16x2 o; o.x = (_Float16)x0; o.y = (_Float16)x1;
        v[j] = __builtin_bit_cast(unsigned, o);
    }
    #pragma unroll
    for (int j = 0; j < CL; ++j)
        *(unsigned*)&As[j * 1024 + ((t * 4) ^ ((j & 7) << 4))] = v[j];
    if (cc == NCH - 1)
        ((float2*)xlast)[cb * 256 + t] = make_float2(x0, x1);   // dup across n-blocks, same value
    __syncthreads();   // one-time full drain: scan ds_writes + B(0) staging

    // ---- K-loop: A resident in LDS, B double-buffered, counted vmcnt ----
    f32x4 acc[4][2];
    #pragma unroll
    for (int i = 0; i < 4; ++i)
        #pragma unroll
        for (int j = 0; j < 2; ++j) acc[i][j] = (f32x4){0.f, 0.f, 0.f, 0.f};

    const int swz = (lr & 7) << 4;        // row&7 == lr&7 for row = m*16+lr
    for (int kt = 0; kt < NK; ++kt) {
        const int cur = kt & 1;
        if (kt + 1 < NK) {
            const int k1 = (kt + 1) * 32;
            load16_lds(bptr + k1, &Bs[cur ^ 1][t * 8]);
            load16_lds(bptr + (size_t)64 * K + k1, &Bs[cur ^ 1][2048 + t * 8]);
            asm volatile("s_waitcnt vmcnt(2)");   // B[kt] done; B[kt+1] in flight
        } else {
            asm volatile("s_waitcnt vmcnt(0)");
        }
        __builtin_amdgcn_s_barrier();
        __builtin_amdgcn_sched_barrier(0);

        f16x8 af[4], bf[2];
        #pragma unroll
        for (int m = 0; m < 4; ++m)
            af[m] = *(const f16x8*)&As[(m * 16 + lr) * 1024 + ((kt * 64 + kg * 16) ^ swz)];
        #pragma unroll
        for (int n = 0; n < 2; ++n)
            bf[n] = *(const f16x8*)&Bs[cur][(wn + n * 16 + lr) * 32 + rchunk];
        #pragma unroll
        for (int m = 0; m < 4; ++m)
            #pragma unroll
            for (int n = 0; n < 2; ++n)
                acc[m][n] = __builtin_amdgcn_mfma_f32_16x16x32_f16(af[m], bf[n], acc[m][n], 0, 0, 0);
        __builtin_amdgcn_s_barrier();    // Bs[cur] reads done before restage
    }

    // epilogue: y = acc + D
    #pragma unroll
    for (int n = 0; n < 2; ++n) {
        const int col = n0 + wn + n * 16 + lr;
        const float dv = Dvec[col];
        #pragma unroll
        for (int m = 0; m < 4; ++m) {
            const int row = m0 + m * 16 + kg * 4;
            #pragma unroll
            for (int j = 0; j < 4; ++j)
                y[(size_t)(row + j) * N + col] = acc[m][n][j] + dv;
        }
    }
}

// ---------------------------------------------------------------------------
extern "C" void kernel_launch(void* const* d_in, const int* in_sizes, int n_in,
                              void* d_out, int out_size, void* d_ws, size_t ws_size,
                              hipStream_t stream) {
    const float* u    = (const float*)d_in[0];   // [B,T,I]
    const float* dt   = (const float*)d_in[1];   // [S]
    const float* Avec = (const float*)d_in[2];   // [S]
    const float* Bmat = (const float*)d_in[3];   // [I,S]
    const float* Cmat = (const float*)d_in[4];   // [S,O]
    const float* Dvec = (const float*)d_in[5];   // [O]
    const float* nw   = (const float*)d_in[6];   // [I]

    float* y     = (float*)d_out;                      // [B,T,O] fp32
    float* xlast = y + (size_t)M_ROWS * O_DIM;         // [B,S]   fp32

    // workspace (~11 MB)
    char* w = (char*)d_ws;
    f16*            up16   = (f16*)(w);                          // [8192,512] f16
    unsigned short* Bt16   = (unsigned short*)(w + 8388608);     // [512,1024] f16 (dts,nw folded)
    unsigned short* Ct16   = (unsigned short*)(w + 9437184);     // [1024,512] f16
    float*          chlast = (float*)(w + 10485760);             // [B,NCH,S]  fp32

    // 1. weight transposes
    prep_w<<<1024, 256, 0, stream>>>(Bmat, dt, nw, Bt16, Cmat, Ct16);

    // 2. GEMM1 (+rmsnorm +chunk finals): up16 = f16(u)@Bt * rs, chlast
    gemm1_rms_chfin<<<512, 256, 0, stream>>>(u, (const f16*)Bt16, up16, chlast, dt, Avec);

    // 3. GEMM2 (+carry +scan): y, xlast
    gemm2_scan<<<1024, 256, 0, stream>>>(up16, chlast, (const f16*)Ct16, Dvec,
                                         dt, Avec, y, xlast);
}